// Round 16
// baseline (217.024 us; speedup 1.0000x reference)
//
#include <hip/hip_runtime.h>
#include <hip/hip_bf16.h>

typedef __attribute__((ext_vector_type(8))) short short8;
typedef __attribute__((ext_vector_type(4))) float f32x4;

#define B_SZ 32
#define T_SZ 4096
#define H_SZ 512
#define NROWS (B_SZ * T_SZ)   // 131072

// packed fp32x2 -> bf16x2 (RNE)
static __device__ __forceinline__ unsigned int pack2(float a, float b) {
  unsigned int r;
  asm("v_cvt_pk_bf16_f32 %0, %1, %2" : "=v"(r) : "v"(a), "v"(b));
  return r;
}
// branch-free tanh, exact saturation: 1 - 2/(e^{2x}+1)
static __device__ __forceinline__ float fast_tanh(float x) {
  float e = __expf(2.0f * x);
  return 1.0f - 2.0f / (e + 1.0f);
}

// ---- W fp32 (512x512) -> bf16 fragments, 32g-CHUNK-MAJOR, full-K ----
// uint4 s = c*2048 + j*1024 + kt*64 + kslot*16 + frow   (c = 0..15, j = 0..1)
// holds W[g = c*32 + j*16 + frow][kt*32 + kslot*8 .. +8]
// one chunk c = 32 g x 512 k = 2048 uint4 = 32 KB contiguous, fragment-linear.
__global__ __launch_bounds__(256) void prep_w_kernel(
    const float* __restrict__ W, uint4* __restrict__ Wfrag) {
  int s = blockIdx.x * 256 + threadIdx.x;   // 0..32767
  int frow  = s & 15;
  int kslot = (s >> 4) & 3;
  int kt    = (s >> 6) & 15;
  int j     = (s >> 10) & 1;
  int c     = s >> 11;
  int g  = c * 32 + j * 16 + frow;
  int k0 = kt * 32 + kslot * 8;
  const float4* Wf4 = reinterpret_cast<const float4*>(W);
  float4 lo = Wf4[g * 128 + (k0 >> 2)];
  float4 hi = Wf4[g * 128 + (k0 >> 2) + 1];
  uint4 u;
  u.x = pack2(lo.x, lo.y); u.y = pack2(lo.z, lo.w);
  u.z = pack2(hi.x, hi.y); u.w = pack2(hi.z, hi.w);
  Wfrag[s] = u;
}

// ---- fused: scores + block softmax + partial numerator ----
// 512 thr = 8 waves, wave owns 32 rows -> block M=256, grid 512 (ONE
// generation: 2 blocks/CU). 16 waves/CU = 4 waves/SIMD: big-burst structure
// (r15) x high occupancy (r6) -- the untested quadrant. A full-K in regs
// (128 VGPR, fits the (512,4) cap). W: 16 chunks of 32 g x 512 k, double-
// buffered 2x32 KB; stage hidden under previous chunk's 64-MFMA burst.
__global__ __launch_bounds__(512, 4) void score_fused_kernel(
    const float* __restrict__ X, const uint4* __restrict__ Wfrag,
    const float* __restrict__ v,
    float* __restrict__ num, float2* __restrict__ md) {
  __shared__ unsigned char WsB[2][32768];  // [j(2)][kt(16)][lane(64)][16B] each
  __shared__ float vLDS[512];
  __shared__ float sLDS[256];
  __shared__ float pLDS[256];
  __shared__ float mred[4], dred[4];

  const int tid   = threadIdx.x;
  const int lane  = tid & 63;
  const int wave  = tid >> 6;
  const int frow  = lane & 15;
  const int kslot = lane >> 4;
  const size_t rowbase = (size_t)blockIdx.x * 256;

  // stage chunk c (32 KB): 4 x 16B linear glds per thread (512 thr)
  #define STAGE(c, buf)                                                         \
    {                                                                           \
      const char* src = (const char*)Wfrag + (size_t)(c) * 32768 + tid * 16;    \
      unsigned char* dst = &WsB[buf][tid * 16];                                 \
      _Pragma("unroll")                                                         \
      for (int i = 0; i < 4; ++i)                                               \
        __builtin_amdgcn_global_load_lds((const unsigned int*)(src + i * 8192), \
                                         (unsigned int*)(dst + i * 8192), 16, 0, 0); \
    }

  // prologue: chunks 0,1 in flight BEFORE the A-load; they land under A-convert
  STAGE(0, 0);
  STAGE(1, 1);
  vLDS[tid] = v[tid];

  // A fragments, 2 rowsets: X[row][kt*32 + kslot*8 .. +8], bf16-packed (128 VGPR)
  short8 afrag0[16], afrag1[16];
  {
    const float4* xr0 = reinterpret_cast<const float4*>(X + (rowbase + wave * 32 + frow) * H_SZ);
    const float4* xr1 = reinterpret_cast<const float4*>(X + (rowbase + wave * 32 + 16 + frow) * H_SZ);
    #pragma unroll
    for (int kt = 0; kt < 16; ++kt) {
      float4 lo0 = xr0[kt * 8 + kslot * 2];
      float4 hi0 = xr0[kt * 8 + kslot * 2 + 1];
      union { uint4 u; short8 s; } c0;
      c0.u.x = pack2(lo0.x, lo0.y); c0.u.y = pack2(lo0.z, lo0.w);
      c0.u.z = pack2(hi0.x, hi0.y); c0.u.w = pack2(hi0.z, hi0.w);
      afrag0[kt] = c0.s;
      float4 lo1 = xr1[kt * 8 + kslot * 2];
      float4 hi1 = xr1[kt * 8 + kslot * 2 + 1];
      union { uint4 u; short8 s; } c1;
      c1.u.x = pack2(lo1.x, lo1.y); c1.u.y = pack2(lo1.z, lo1.w);
      c1.u.z = pack2(hi1.x, hi1.y); c1.u.w = pack2(hi1.z, hi1.w);
      afrag1[kt] = c1.s;
    }
  }
  // A-converts already drained stage 0/1 (older vmem); sync LDS + waves
  asm volatile("s_waitcnt vmcnt(0) lgkmcnt(0)" ::: "memory");
  __builtin_amdgcn_s_barrier();
  __builtin_amdgcn_sched_barrier(0);

  float red0[4] = {0.f, 0.f, 0.f, 0.f};
  float red1[4] = {0.f, 0.f, 0.f, 0.f};

  for (int ch = 0; ch < 16; ++ch) {
    const int buf = ch & 1;
    float vv0 = vLDS[ch * 32 + frow];
    float vv1 = vLDS[ch * 32 + 16 + frow];

    f32x4 acc[2][2];   // [rowset][j]
    #pragma unroll
    for (int a = 0; a < 2; ++a)
      #pragma unroll
      for (int j = 0; j < 2; ++j)
        acc[a][j] = (f32x4){0.f, 0.f, 0.f, 0.f};

    const unsigned char* bb = &WsB[buf][lane * 16];
    __builtin_amdgcn_s_setprio(1);
    #pragma unroll
    for (int kt = 0; kt < 16; ++kt) {
      short8 b0 = *reinterpret_cast<const short8*>(bb + kt * 1024);          // j=0
      short8 b1 = *reinterpret_cast<const short8*>(bb + 16384 + kt * 1024);  // j=1
      acc[0][0] = __builtin_amdgcn_mfma_f32_16x16x32_bf16(afrag0[kt], b0, acc[0][0], 0, 0, 0);
      acc[1][0] = __builtin_amdgcn_mfma_f32_16x16x32_bf16(afrag1[kt], b0, acc[1][0], 0, 0, 0);
      acc[0][1] = __builtin_amdgcn_mfma_f32_16x16x32_bf16(afrag0[kt], b1, acc[0][1], 0, 0, 0);
      acc[1][1] = __builtin_amdgcn_mfma_f32_16x16x32_bf16(afrag1[kt], b1, acc[1][1], 0, 0, 0);
    }
    __builtin_amdgcn_s_setprio(0);

    // chunk epilogue: D[m][n] n=frow within j-group, m=kslot*4+r
    #pragma unroll
    for (int r = 0; r < 4; ++r) {
      red0[r] = fmaf(vv0, fast_tanh(acc[0][0][r]), red0[r]);
      red0[r] = fmaf(vv1, fast_tanh(acc[0][1][r]), red0[r]);
      red1[r] = fmaf(vv0, fast_tanh(acc[1][0][r]), red1[r]);
      red1[r] = fmaf(vv1, fast_tanh(acc[1][1][r]), red1[r]);
    }

    // stage(ch+1) had the whole compute to land -> vmcnt(0) is ~free.
    // barrier: all waves done reading buf, then reuse it for chunk ch+2.
    asm volatile("s_waitcnt vmcnt(0)" ::: "memory");
    __builtin_amdgcn_s_barrier();
    __builtin_amdgcn_sched_barrier(0);
    if (ch + 2 < 16) STAGE(ch + 2, buf);
  }
  #undef STAGE

  // reduce over the 16 g-lanes (frow) within each kslot group
  #pragma unroll
  for (int r = 0; r < 4; ++r) {
    #pragma unroll
    for (int d = 1; d < 16; d <<= 1) {
      red0[r] += __shfl_xor(red0[r], d);
      red1[r] += __shfl_xor(red1[r], d);
    }
  }
  if (frow == 0) {
    float* sp = sLDS + wave * 32 + kslot * 4;
    sp[0]  = red0[0]; sp[1]  = red0[1]; sp[2]  = red0[2]; sp[3]  = red0[3];
    sp[16] = red1[0]; sp[17] = red1[1]; sp[18] = red1[2]; sp[19] = red1[3];
  }
  __syncthreads();

  // ---- block-local softmax stats over the 256 rows ----
  if (tid < 256) {
    float s = sLDS[tid];
    float m = s;
    #pragma unroll
    for (int d = 1; d < 64; d <<= 1) m = fmaxf(m, __shfl_xor(m, d));
    if ((tid & 63) == 0) mred[tid >> 6] = m;
  }
  __syncthreads();
  const float m_loc = fmaxf(fmaxf(mred[0], mred[1]), fmaxf(mred[2], mred[3]));
  if (tid < 256) {
    float p = __expf(sLDS[tid] - m_loc);
    pLDS[tid] = p;
    #pragma unroll
    for (int d = 1; d < 64; d <<= 1) p += __shfl_xor(p, d);
    if ((tid & 63) == 0) dred[tid >> 6] = p;
  }
  __syncthreads();

  // ---- partial numerator: thread owns h = tid; X tile L2/L3-hot ----
  {
    float a = 0.f;
    const float* xb = X + rowbase * H_SZ + tid;
    #pragma unroll 8
    for (int t = 0; t < 256; ++t)
      a = fmaf(pLDS[t], xb[(size_t)t * H_SZ], a);
    num[(size_t)blockIdx.x * H_SZ + tid] = a;
  }
  if (tid == 0) {
    float2 r; r.x = m_loc; r.y = dred[0] + dred[1] + dred[2] + dred[3];
    md[blockIdx.x] = r;
  }
}

// ---- combine 16 block-partials per batch with global-max rescale ----
__global__ __launch_bounds__(512) void combine_kernel(
    const float* __restrict__ num, const float2* __restrict__ md,
    float* __restrict__ out) {
  const int b = blockIdx.x;   // 32
  const int h = threadIdx.x;  // 512
  float M = -1e30f;
  #pragma unroll
  for (int c = 0; c < 16; ++c) M = fmaxf(M, md[b * 16 + c].x);
  float den = 0.f, acc = 0.f;
  #pragma unroll 4
  for (int c = 0; c < 16; ++c) {
    float2 m2 = md[b * 16 + c];
    float w = __expf(m2.x - M);
    den += w * m2.y;
    acc = fmaf(w, num[(size_t)(b * 16 + c) * H_SZ + h], acc);
  }
  out[b * H_SZ + h] = acc / den;
}

extern "C" void kernel_launch(void* const* d_in, const int* in_sizes, int n_in,
                              void* d_out, int out_size, void* d_ws, size_t ws_size,
                              hipStream_t stream) {
  const float* X = (const float*)d_in[0];   // (32,4096,512)
  const float* W = (const float*)d_in[1];   // (512,512)
  const float* v = (const float*)d_in[2];   // (512,)
  float* out = (float*)d_out;               // (32,512) fp32
  unsigned char* ws = (unsigned char*)d_ws;

  uint4* Wfrag = (uint4*)(ws);                               // 512 KB
  float* num   = (float*)(ws + (512u << 10));                // 512*512*4 = 1 MB
  float2* md   = (float2*)(ws + (512u << 10) + (1u << 20));  // 4 KB

  prep_w_kernel<<<128, 256, 0, stream>>>(W, Wfrag);
  score_fused_kernel<<<NROWS / 256, 512, 0, stream>>>(X, Wfrag, v, num, md);
  combine_kernel<<<B_SZ, 512, 0, stream>>>(num, md, out);
}

// Round 17
// 140.051 us; speedup vs baseline: 1.5496x; 1.5496x over previous
//
#include <hip/hip_runtime.h>
#include <hip/hip_bf16.h>

typedef __attribute__((ext_vector_type(8))) short short8;
typedef __attribute__((ext_vector_type(4))) float f32x4;

#define B_SZ 32
#define T_SZ 4096
#define H_SZ 512
#define NROWS (B_SZ * T_SZ)   // 131072

// packed fp32x2 -> bf16x2 (RNE)
static __device__ __forceinline__ unsigned int pack2(float a, float b) {
  unsigned int r;
  asm("v_cvt_pk_bf16_f32 %0, %1, %2" : "=v"(r) : "v"(a), "v"(b));
  return r;
}
// branch-free tanh, exact saturation: 1 - 2/(e^{2x}+1)
static __device__ __forceinline__ float fast_tanh(float x) {
  float e = __expf(2.0f * x);
  return 1.0f - 2.0f / (e + 1.0f);
}

// ---- W fp32 (512x512) -> bf16 fragments, 16g-CHUNK-MAJOR, full-K ----
// uint4 s = c*1024 + kt*64 + kslot*16 + frow   (c = 0..31)
// holds W[g = c*16 + frow][kt*32 + kslot*8 .. +8]
// one chunk c = 16 g x 512 k = 1024 uint4 = 16 KB contiguous, fragment-linear.
__global__ __launch_bounds__(256) void prep_w_kernel(
    const float* __restrict__ W, uint4* __restrict__ Wfrag) {
  int s = blockIdx.x * 256 + threadIdx.x;   // 0..32767
  int frow  = s & 15;
  int kslot = (s >> 4) & 3;
  int kt    = (s >> 6) & 15;
  int c     = s >> 10;
  int g  = c * 16 + frow;
  int k0 = kt * 32 + kslot * 8;
  const float4* Wf4 = reinterpret_cast<const float4*>(W);
  float4 lo = Wf4[g * 128 + (k0 >> 2)];
  float4 hi = Wf4[g * 128 + (k0 >> 2) + 1];
  uint4 u;
  u.x = pack2(lo.x, lo.y); u.y = pack2(lo.z, lo.w);
  u.z = pack2(hi.x, hi.y); u.w = pack2(hi.z, hi.w);
  Wfrag[s] = u;
}

// ---- fused: scores + block softmax + partial numerator ----
// 256 thr = 4 waves, wave owns 32 rows (A full-K in regs, ~120 VGPR).
// W: 32 chunks of 16 g x 512 k, double-buffered 2x16 KB; stage hidden under
// previous chunk's 32-MFMA burst. Total LDS ~35.9 KB -> 4 blocks/CU: four
// INDEPENDENT barrier domains per CU = cross-block latency hiding that the
// 2-block r15 lacked. Grid 1024 = fully resident (one generation).
__global__ __launch_bounds__(256, 2) void score_fused_kernel(
    const float* __restrict__ X, const uint4* __restrict__ Wfrag,
    const float* __restrict__ v,
    float* __restrict__ num, float2* __restrict__ md) {
  __shared__ unsigned char WsB[2][16384];  // [kt(16)][lane(64)][16B] each
  __shared__ float vLDS[512];
  __shared__ float sLDS[128];
  __shared__ float pLDS[128];
  __shared__ float mred[2], dred[2];

  const int tid   = threadIdx.x;
  const int lane  = tid & 63;
  const int wave  = tid >> 6;
  const int frow  = lane & 15;
  const int kslot = lane >> 4;
  const size_t rowbase = (size_t)blockIdx.x * 128;

  // stage chunk c (16 KB): 4 x 16B linear glds per thread
  #define STAGE(c, buf)                                                         \
    {                                                                           \
      const char* src = (const char*)Wfrag + (size_t)(c) * 16384 + tid * 16;    \
      unsigned char* dst = &WsB[buf][tid * 16];                                 \
      _Pragma("unroll")                                                         \
      for (int i = 0; i < 4; ++i)                                               \
        __builtin_amdgcn_global_load_lds((const unsigned int*)(src + i * 4096), \
                                         (unsigned int*)(dst + i * 4096), 16, 0, 0); \
    }

  // prologue: chunks 0,1 in flight BEFORE the A-load; they land under A-convert
  STAGE(0, 0);
  STAGE(1, 1);
  reinterpret_cast<float2*>(vLDS)[tid] = reinterpret_cast<const float2*>(v)[tid];

  // A fragments, 2 rowsets: X[row][kt*32 + kslot*8 .. +8], bf16-packed (128 VGPR)
  short8 afrag0[16], afrag1[16];
  {
    const float4* xr0 = reinterpret_cast<const float4*>(X + (rowbase + wave * 32 + frow) * H_SZ);
    const float4* xr1 = reinterpret_cast<const float4*>(X + (rowbase + wave * 32 + 16 + frow) * H_SZ);
    #pragma unroll
    for (int kt = 0; kt < 16; ++kt) {
      float4 lo0 = xr0[kt * 8 + kslot * 2];
      float4 hi0 = xr0[kt * 8 + kslot * 2 + 1];
      union { uint4 u; short8 s; } c0;
      c0.u.x = pack2(lo0.x, lo0.y); c0.u.y = pack2(lo0.z, lo0.w);
      c0.u.z = pack2(hi0.x, hi0.y); c0.u.w = pack2(hi0.z, hi0.w);
      afrag0[kt] = c0.s;
      float4 lo1 = xr1[kt * 8 + kslot * 2];
      float4 hi1 = xr1[kt * 8 + kslot * 2 + 1];
      union { uint4 u; short8 s; } c1;
      c1.u.x = pack2(lo1.x, lo1.y); c1.u.y = pack2(lo1.z, lo1.w);
      c1.u.z = pack2(hi1.x, hi1.y); c1.u.w = pack2(hi1.z, hi1.w);
      afrag1[kt] = c1.s;
    }
  }
  // A-converts already drained stage 0/1 (older vmem); sync LDS + waves
  asm volatile("s_waitcnt vmcnt(0) lgkmcnt(0)" ::: "memory");
  __builtin_amdgcn_s_barrier();
  __builtin_amdgcn_sched_barrier(0);

  float red0[4] = {0.f, 0.f, 0.f, 0.f};
  float red1[4] = {0.f, 0.f, 0.f, 0.f};

  for (int ch = 0; ch < 32; ++ch) {
    const int buf = ch & 1;
    float vg = vLDS[ch * 16 + frow];

    // 4 independent chains: [rowset][kt-parity]
    f32x4 acc[2][2];
    #pragma unroll
    for (int a = 0; a < 2; ++a)
      #pragma unroll
      for (int p = 0; p < 2; ++p)
        acc[a][p] = (f32x4){0.f, 0.f, 0.f, 0.f};

    const unsigned char* bb = &WsB[buf][lane * 16];
    __builtin_amdgcn_s_setprio(1);
    #pragma unroll
    for (int kt = 0; kt < 16; ++kt) {
      short8 b = *reinterpret_cast<const short8*>(bb + kt * 1024);  // linear, conflict-free
      const int p = kt & 1;
      acc[0][p] = __builtin_amdgcn_mfma_f32_16x16x32_bf16(afrag0[kt], b, acc[0][p], 0, 0, 0);
      acc[1][p] = __builtin_amdgcn_mfma_f32_16x16x32_bf16(afrag1[kt], b, acc[1][p], 0, 0, 0);
    }
    __builtin_amdgcn_s_setprio(0);

    // chunk epilogue: D[m][n] n=frow, m=kslot*4+r
    #pragma unroll
    for (int r = 0; r < 4; ++r) {
      red0[r] = fmaf(vg, fast_tanh(acc[0][0][r] + acc[0][1][r]), red0[r]);
      red1[r] = fmaf(vg, fast_tanh(acc[1][0][r] + acc[1][1][r]), red1[r]);
    }

    // stage(ch+1) had the whole compute to land -> vmcnt(0) is ~free.
    // barrier: all waves done reading buf, then reuse it for chunk ch+2.
    asm volatile("s_waitcnt vmcnt(0)" ::: "memory");
    __builtin_amdgcn_s_barrier();
    __builtin_amdgcn_sched_barrier(0);
    if (ch + 2 < 32) STAGE(ch + 2, buf);
  }
  #undef STAGE

  // reduce over the 16 g-lanes (frow) within each kslot group
  #pragma unroll
  for (int r = 0; r < 4; ++r) {
    #pragma unroll
    for (int d = 1; d < 16; d <<= 1) {
      red0[r] += __shfl_xor(red0[r], d);
      red1[r] += __shfl_xor(red1[r], d);
    }
  }
  if (frow == 0) {
    float* sp = sLDS + wave * 32 + kslot * 4;
    sp[0]  = red0[0]; sp[1]  = red0[1]; sp[2]  = red0[2]; sp[3]  = red0[3];
    sp[16] = red1[0]; sp[17] = red1[1]; sp[18] = red1[2]; sp[19] = red1[3];
  }
  __syncthreads();

  // ---- block-local softmax stats over the 128 rows ----
  if (tid < 128) {
    float s = sLDS[tid];
    float m = s;
    #pragma unroll
    for (int d = 1; d < 64; d <<= 1) m = fmaxf(m, __shfl_xor(m, d));
    if ((tid & 63) == 0) mred[tid >> 6] = m;
  }
  __syncthreads();
  const float m_loc = fmaxf(mred[0], mred[1]);
  if (tid < 128) {
    float p = __expf(sLDS[tid] - m_loc);
    pLDS[tid] = p;
    #pragma unroll
    for (int d = 1; d < 64; d <<= 1) p += __shfl_xor(p, d);
    if ((tid & 63) == 0) dred[tid >> 6] = p;
  }
  __syncthreads();

  // ---- partial numerator: thread owns h = 2*tid..+1; X tile L2/L3-hot ----
  {
    float ax = 0.f, ay = 0.f;
    const float2* xb = reinterpret_cast<const float2*>(X + rowbase * H_SZ) + tid;
    #pragma unroll 8
    for (int t = 0; t < 128; ++t) {
      float p = pLDS[t];
      float2 xv = xb[(size_t)t * (H_SZ / 2)];
      ax = fmaf(p, xv.x, ax);
      ay = fmaf(p, xv.y, ay);
    }
    float2 r; r.x = ax; r.y = ay;
    reinterpret_cast<float2*>(num + (size_t)blockIdx.x * H_SZ)[tid] = r;
  }
  if (tid == 0) {
    float2 r; r.x = m_loc; r.y = dred[0] + dred[1];
    md[blockIdx.x] = r;
  }
}

// ---- combine 32 block-partials per batch with global-max rescale ----
__global__ __launch_bounds__(512) void combine_kernel(
    const float* __restrict__ num, const float2* __restrict__ md,
    float* __restrict__ out) {
  const int b = blockIdx.x;   // 32
  const int h = threadIdx.x;  // 512
  float M = -1e30f;
  #pragma unroll
  for (int c = 0; c < 32; ++c) M = fmaxf(M, md[b * 32 + c].x);
  float den = 0.f, acc = 0.f;
  #pragma unroll 4
  for (int c = 0; c < 32; ++c) {
    float2 m2 = md[b * 32 + c];
    float w = __expf(m2.x - M);
    den += w * m2.y;
    acc = fmaf(w, num[(size_t)(b * 32 + c) * H_SZ + h], acc);
  }
  out[b * H_SZ + h] = acc / den;
}

extern "C" void kernel_launch(void* const* d_in, const int* in_sizes, int n_in,
                              void* d_out, int out_size, void* d_ws, size_t ws_size,
                              hipStream_t stream) {
  const float* X = (const float*)d_in[0];   // (32,4096,512)
  const float* W = (const float*)d_in[1];   // (512,512)
  const float* v = (const float*)d_in[2];   // (512,)
  float* out = (float*)d_out;               // (32,512) fp32
  unsigned char* ws = (unsigned char*)d_ws;

  uint4* Wfrag = (uint4*)(ws);                               // 512 KB
  float* num   = (float*)(ws + (512u << 10));                // 2 MB
  float2* md   = (float2*)(ws + (512u << 10) + (2u << 20));  // 8 KB

  prep_w_kernel<<<128, 256, 0, stream>>>(W, Wfrag);
  score_fused_kernel<<<NROWS / 128, 256, 0, stream>>>(X, Wfrag, v, num, md);
  combine_kernel<<<B_SZ, 512, 0, stream>>>(num, md, out);
}

// Round 18
// 135.087 us; speedup vs baseline: 1.6065x; 1.0367x over previous
//
#include <hip/hip_runtime.h>
#include <hip/hip_bf16.h>

typedef __attribute__((ext_vector_type(8))) short short8;
typedef __attribute__((ext_vector_type(4))) float f32x4;

#define B_SZ 32
#define T_SZ 4096
#define H_SZ 512
#define NROWS (B_SZ * T_SZ)   // 131072

// packed fp32x2 -> bf16x2 (RNE)
static __device__ __forceinline__ unsigned int pack2(float a, float b) {
  unsigned int r;
  asm("v_cvt_pk_bf16_f32 %0, %1, %2" : "=v"(r) : "v"(a), "v"(b));
  return r;
}
// branch-free tanh, exact saturation: 1 - 2/(e^{2x}+1)
static __device__ __forceinline__ float fast_tanh(float x) {
  float e = __expf(2.0f * x);
  return 1.0f - 2.0f / (e + 1.0f);
}

// ---- W fp32 (512x512) -> bf16 fragments, 32g-CHUNK-MAJOR, full-K ----
// uint4 s = c*2048 + j*1024 + kt*64 + kslot*16 + frow   (c = 0..15, j = 0..1)
// holds W[g = c*32 + j*16 + frow][kt*32 + kslot*8 .. +8]
// one chunk c = 32 g x 512 k = 2048 uint4 = 32 KB contiguous, fragment-linear.
__global__ __launch_bounds__(256) void prep_w_kernel(
    const float* __restrict__ W, uint4* __restrict__ Wfrag) {
  int s = blockIdx.x * 256 + threadIdx.x;   // 0..32767
  int frow  = s & 15;
  int kslot = (s >> 4) & 3;
  int kt    = (s >> 6) & 15;
  int j     = (s >> 10) & 1;
  int c     = s >> 11;
  int g  = c * 32 + j * 16 + frow;
  int k0 = kt * 32 + kslot * 8;
  const float4* Wf4 = reinterpret_cast<const float4*>(W);
  float4 lo = Wf4[g * 128 + (k0 >> 2)];
  float4 hi = Wf4[g * 128 + (k0 >> 2) + 1];
  uint4 u;
  u.x = pack2(lo.x, lo.y); u.y = pack2(lo.z, lo.w);
  u.z = pack2(hi.x, hi.y); u.w = pack2(hi.z, hi.w);
  Wfrag[s] = u;
}

// ---- fused: scores + block softmax + partial numerator ----
// r15 core (champion, 133.9 us): 256 thr = 4 waves, wave owns 32 rows,
// A full-K in regs; 16 chunks of 32 g x 512 k double-buffered 2x32 KB,
// stage hidden under previous chunk's 64-MFMA burst.
// NEW: tanh epilogue of chunk ch-1 deferred into chunk ch's MFMA-burst
// window (ping-pong accP) -- VALU slice hides under the MFMA pipe (m114).
__global__ __launch_bounds__(256, 2) void score_fused_kernel(
    const float* __restrict__ X, const uint4* __restrict__ Wfrag,
    const float* __restrict__ v,
    float* __restrict__ num, float2* __restrict__ md) {
  __shared__ unsigned char WsB[2][32768];  // [j(2)][kt(16)][lane(64)][16B] each
  __shared__ float vLDS[512];
  __shared__ float sLDS[128];
  __shared__ float pLDS[128];
  __shared__ float mred[2], dred[2];

  const int tid   = threadIdx.x;
  const int lane  = tid & 63;
  const int wave  = tid >> 6;
  const int frow  = lane & 15;
  const int kslot = lane >> 4;
  const size_t rowbase = (size_t)blockIdx.x * 128;

  // stage chunk c (32 KB): 8 x 16B linear glds per thread
  #define STAGE(c, buf)                                                         \
    {                                                                           \
      const char* src = (const char*)Wfrag + (size_t)(c) * 32768 + tid * 16;    \
      unsigned char* dst = &WsB[buf][tid * 16];                                 \
      _Pragma("unroll")                                                         \
      for (int i = 0; i < 8; ++i)                                               \
        __builtin_amdgcn_global_load_lds((const unsigned int*)(src + i * 4096), \
                                         (unsigned int*)(dst + i * 4096), 16, 0, 0); \
    }

  // prologue: chunks 0,1 in flight BEFORE the A-load; they land under A-convert
  STAGE(0, 0);
  STAGE(1, 1);
  reinterpret_cast<float2*>(vLDS)[tid] = reinterpret_cast<const float2*>(v)[tid];

  // A fragments, 2 rowsets: X[row][kt*32 + kslot*8 .. +8], bf16-packed (128 VGPR)
  short8 afrag0[16], afrag1[16];
  {
    const float4* xr0 = reinterpret_cast<const float4*>(X + (rowbase + wave * 32 + frow) * H_SZ);
    const float4* xr1 = reinterpret_cast<const float4*>(X + (rowbase + wave * 32 + 16 + frow) * H_SZ);
    #pragma unroll
    for (int kt = 0; kt < 16; ++kt) {
      float4 lo0 = xr0[kt * 8 + kslot * 2];
      float4 hi0 = xr0[kt * 8 + kslot * 2 + 1];
      union { uint4 u; short8 s; } c0;
      c0.u.x = pack2(lo0.x, lo0.y); c0.u.y = pack2(lo0.z, lo0.w);
      c0.u.z = pack2(hi0.x, hi0.y); c0.u.w = pack2(hi0.z, hi0.w);
      afrag0[kt] = c0.s;
      float4 lo1 = xr1[kt * 8 + kslot * 2];
      float4 hi1 = xr1[kt * 8 + kslot * 2 + 1];
      union { uint4 u; short8 s; } c1;
      c1.u.x = pack2(lo1.x, lo1.y); c1.u.y = pack2(lo1.z, lo1.w);
      c1.u.z = pack2(hi1.x, hi1.y); c1.u.w = pack2(hi1.z, hi1.w);
      afrag1[kt] = c1.s;
    }
  }
  // A-converts already drained stage 0/1 (older vmem); sync LDS + waves
  asm volatile("s_waitcnt vmcnt(0) lgkmcnt(0)" ::: "memory");
  __builtin_amdgcn_s_barrier();
  __builtin_amdgcn_sched_barrier(0);

  float red0[4] = {0.f, 0.f, 0.f, 0.f};
  float red1[4] = {0.f, 0.f, 0.f, 0.f};

  // ping-pong state: previous chunk's accumulators + its v values
  f32x4 accP[2][2];
  float vp0 = 0.f, vp1 = 0.f;

  for (int ch = 0; ch < 16; ++ch) {
    const int buf = ch & 1;
    float vv0 = vLDS[ch * 32 + frow];
    float vv1 = vLDS[ch * 32 + 16 + frow];

    f32x4 accC[2][2];   // [rowset][j]
    #pragma unroll
    for (int a = 0; a < 2; ++a)
      #pragma unroll
      for (int j = 0; j < 2; ++j)
        accC[a][j] = (f32x4){0.f, 0.f, 0.f, 0.f};

    const unsigned char* bb = &WsB[buf][lane * 16];
    __builtin_amdgcn_s_setprio(1);
    #pragma unroll
    for (int kt = 0; kt < 16; ++kt) {
      short8 b0 = *reinterpret_cast<const short8*>(bb + kt * 1024);          // j=0
      short8 b1 = *reinterpret_cast<const short8*>(bb + 16384 + kt * 1024);  // j=1
      accC[0][0] = __builtin_amdgcn_mfma_f32_16x16x32_bf16(afrag0[kt], b0, accC[0][0], 0, 0, 0);
      accC[1][0] = __builtin_amdgcn_mfma_f32_16x16x32_bf16(afrag1[kt], b0, accC[1][0], 0, 0, 0);
      accC[0][1] = __builtin_amdgcn_mfma_f32_16x16x32_bf16(afrag0[kt], b1, accC[0][1], 0, 0, 0);
      accC[1][1] = __builtin_amdgcn_mfma_f32_16x16x32_bf16(afrag1[kt], b1, accC[1][1], 0, 0, 0);
    }
    __builtin_amdgcn_s_setprio(0);

    // deferred epilogue: tanh of chunk ch-1 (independent of accC -> VALU
    // co-issues while the MFMA pipe drains the burst above)
    if (ch > 0) {
      #pragma unroll
      for (int r = 0; r < 4; ++r) {
        red0[r] = fmaf(vp0, fast_tanh(accP[0][0][r]), red0[r]);
        red0[r] = fmaf(vp1, fast_tanh(accP[0][1][r]), red0[r]);
        red1[r] = fmaf(vp0, fast_tanh(accP[1][0][r]), red1[r]);
        red1[r] = fmaf(vp1, fast_tanh(accP[1][1][r]), red1[r]);
      }
    }
    #pragma unroll
    for (int a = 0; a < 2; ++a)
      #pragma unroll
      for (int j = 0; j < 2; ++j)
        accP[a][j] = accC[a][j];
    vp0 = vv0; vp1 = vv1;

    // stage(ch+1) had the whole compute to land -> vmcnt(0) is ~free.
    // barrier: all waves done reading buf, then reuse it for chunk ch+2.
    asm volatile("s_waitcnt vmcnt(0)" ::: "memory");
    __builtin_amdgcn_s_barrier();
    __builtin_amdgcn_sched_barrier(0);
    if (ch + 2 < 16) STAGE(ch + 2, buf);
  }
  #undef STAGE

  // final deferred epilogue (chunk 15)
  #pragma unroll
  for (int r = 0; r < 4; ++r) {
    red0[r] = fmaf(vp0, fast_tanh(accP[0][0][r]), red0[r]);
    red0[r] = fmaf(vp1, fast_tanh(accP[0][1][r]), red0[r]);
    red1[r] = fmaf(vp0, fast_tanh(accP[1][0][r]), red1[r]);
    red1[r] = fmaf(vp1, fast_tanh(accP[1][1][r]), red1[r]);
  }

  // reduce over the 16 g-lanes (frow) within each kslot group
  #pragma unroll
  for (int r = 0; r < 4; ++r) {
    #pragma unroll
    for (int d = 1; d < 16; d <<= 1) {
      red0[r] += __shfl_xor(red0[r], d);
      red1[r] += __shfl_xor(red1[r], d);
    }
  }
  if (frow == 0) {
    float* sp = sLDS + wave * 32 + kslot * 4;
    sp[0]  = red0[0]; sp[1]  = red0[1]; sp[2]  = red0[2]; sp[3]  = red0[3];
    sp[16] = red1[0]; sp[17] = red1[1]; sp[18] = red1[2]; sp[19] = red1[3];
  }
  __syncthreads();

  // ---- block-local softmax stats over the 128 rows ----
  if (tid < 128) {
    float s = sLDS[tid];
    float m = s;
    #pragma unroll
    for (int d = 1; d < 64; d <<= 1) m = fmaxf(m, __shfl_xor(m, d));
    if ((tid & 63) == 0) mred[tid >> 6] = m;
  }
  __syncthreads();
  const float m_loc = fmaxf(mred[0], mred[1]);
  if (tid < 128) {
    float p = __expf(sLDS[tid] - m_loc);
    pLDS[tid] = p;
    #pragma unroll
    for (int d = 1; d < 64; d <<= 1) p += __shfl_xor(p, d);
    if ((tid & 63) == 0) dred[tid >> 6] = p;
  }
  __syncthreads();

  // ---- partial numerator: thread owns h = 2*tid..+1; X tile L2/L3-hot ----
  {
    float ax = 0.f, ay = 0.f;
    const float2* xb = reinterpret_cast<const float2*>(X + rowbase * H_SZ) + tid;
    #pragma unroll 8
    for (int t = 0; t < 128; ++t) {
      float p = pLDS[t];
      float2 xv = xb[(size_t)t * (H_SZ / 2)];
      ax = fmaf(p, xv.x, ax);
      ay = fmaf(p, xv.y, ay);
    }
    float2 r; r.x = ax; r.y = ay;
    reinterpret_cast<float2*>(num + (size_t)blockIdx.x * H_SZ)[tid] = r;
  }
  if (tid == 0) {
    float2 r; r.x = m_loc; r.y = dred[0] + dred[1];
    md[blockIdx.x] = r;
  }
}

// ---- combine 32 block-partials per batch with global-max rescale ----
__global__ __launch_bounds__(512) void combine_kernel(
    const float* __restrict__ num, const float2* __restrict__ md,
    float* __restrict__ out) {
  const int b = blockIdx.x;   // 32
  const int h = threadIdx.x;  // 512
  float M = -1e30f;
  #pragma unroll
  for (int c = 0; c < 32; ++c) M = fmaxf(M, md[b * 32 + c].x);
  float den = 0.f, acc = 0.f;
  #pragma unroll 4
  for (int c = 0; c < 32; ++c) {
    float2 m2 = md[b * 32 + c];
    float w = __expf(m2.x - M);
    den += w * m2.y;
    acc = fmaf(w, num[(size_t)(b * 32 + c) * H_SZ + h], acc);
  }
  out[b * H_SZ + h] = acc / den;
}

extern "C" void kernel_launch(void* const* d_in, const int* in_sizes, int n_in,
                              void* d_out, int out_size, void* d_ws, size_t ws_size,
                              hipStream_t stream) {
  const float* X = (const float*)d_in[0];   // (32,4096,512)
  const float* W = (const float*)d_in[1];   // (512,512)
  const float* v = (const float*)d_in[2];   // (512,)
  float* out = (float*)d_out;               // (32,512) fp32
  unsigned char* ws = (unsigned char*)d_ws;

  uint4* Wfrag = (uint4*)(ws);                               // 512 KB
  float* num   = (float*)(ws + (512u << 10));                // 2 MB
  float2* md   = (float2*)(ws + (512u << 10) + (2u << 20));  // 8 KB

  prep_w_kernel<<<128, 256, 0, stream>>>(W, Wfrag);
  score_fused_kernel<<<NROWS / 128, 256, 0, stream>>>(X, Wfrag, v, num, md);
  combine_kernel<<<B_SZ, 512, 0, stream>>>(num, md, out);
}